// Round 2
// baseline (102.619 us; speedup 1.0000x reference)
//
#include <hip/hip_runtime.h>
#include <hip/hip_bf16.h>
#include <math.h>

// dims fixed by setup_inputs: N=8, H=8, D=64, L=M=1024, C=64

typedef __attribute__((ext_vector_type(4)))  float    f32x4;
typedef __attribute__((ext_vector_type(16))) float    f32x16;
typedef __attribute__((ext_vector_type(8)))  __bf16   bf16x8;
typedef __attribute__((ext_vector_type(8)))  short    s16x8;
typedef __attribute__((ext_vector_type(4)))  unsigned u32x4;

// ws layout: Kt bf16 [64][1024][64] = 8 MiB, then partials + scale
#define KT_OFF 0u
#define SS_OFF (8u*1024u*1024u)            // fp32 partial[256]
#define SC_OFF (SS_OFF + 1024u)            // fp32 scale2[8]

static __device__ __forceinline__ short bf16s(float f) {
  return __builtin_bit_cast(short, (__bf16)f);
}
static __device__ __forceinline__ unsigned pkbf(float lo, float hi) {
  unsigned l = (unsigned)__builtin_bit_cast(unsigned short, (__bf16)lo);
  unsigned h = (unsigned)__builtin_bit_cast(unsigned short, (__bf16)hi);
  return l | (h << 16);
}
static __device__ __forceinline__ bf16x8 cvt8(const float* p) {
  f32x4 a = *(const f32x4*)p;
  f32x4 b = *(const f32x4*)(p + 4);
  bf16x8 r;
  r[0]=(__bf16)a[0]; r[1]=(__bf16)a[1]; r[2]=(__bf16)a[2]; r[3]=(__bf16)a[3];
  r[4]=(__bf16)b[0]; r[5]=(__bf16)b[1]; r[6]=(__bf16)b[2]; r[7]=(__bf16)b[3];
  return r;
}
static __device__ __forceinline__ f32x16 z16() {
  f32x16 z;
  #pragma unroll
  for (int i = 0; i < 16; ++i) z[i] = 0.f;
  return z;
}
static __device__ __forceinline__ bf16x8 mk8(unsigned a, unsigned b, unsigned c, unsigned d) {
  u32x4 u; u[0]=a; u[1]=b; u[2]=c; u[3]=d;
  return __builtin_bit_cast(bf16x8, u);
}

// ---------------- K0: K [bh][d][m] fp32 -> Kt [bh][m][d] bf16 ----------------
__global__ __launch_bounds__(256) void k0_transpose(const float* __restrict__ K,
                                                    short* __restrict__ Kt) {
  int bh = blockIdx.x >> 4;
  int m0 = (blockIdx.x & 15) << 6;
  __shared__ short tile[64][72];          // [m][d], +8 pad
  int tid = threadIdx.x;
  int d = tid >> 2;
  #pragma unroll
  for (int it = 0; it < 4; ++it) {
    int mc4 = (tid & 3) + (it << 2);      // 16 chunks of 4 m
    const f32x4 v = *(const f32x4*)(K + (((size_t)(bh*64 + d)) << 10) + m0 + (mc4 << 2));
    #pragma unroll
    for (int j = 0; j < 4; ++j) tile[mc4*4 + j][d] = bf16s(v[j]);
  }
  __syncthreads();
  int m = tid >> 2, q = tid & 3;
  s16x8 o0, o1;
  #pragma unroll
  for (int j = 0; j < 8; ++j) { o0[j] = tile[m][q*16 + j]; o1[j] = tile[m][q*16 + 8 + j]; }
  short* dst = Kt + ((size_t)bh << 16) + ((size_t)(m0 + m) << 6) + (q << 4);
  *(s16x8*)dst = o0;
  *(s16x8*)(dst + 8) = o1;
}

// ---------------- K1: partial[blk] = <GQ_tile, GK_tile> (deterministic) ------
__global__ __launch_bounds__(256) void k1_gram(const float* __restrict__ Q,
                                               const float* __restrict__ K,
                                               float* __restrict__ partial) {
  int bh = blockIdx.x >> 2;
  int t  = blockIdx.x & 3;
  int tr = (t >> 1) << 5, tc = (t & 1) << 5;
  int tid = threadIdx.x, w = tid >> 6, lane = tid & 63;
  int l31 = lane & 31, hi = lane >> 5;
  const float* qb = Q + ((size_t)bh << 16);
  const float* kb = K + ((size_t)bh << 16);
  const float* qa = qb + ((size_t)(tr + l31) << 10);
  const float* qc = qb + ((size_t)(tc + l31) << 10);
  const float* ka = kb + ((size_t)(tr + l31) << 10);
  const float* kc = kb + ((size_t)(tc + l31) << 10);
  f32x16 gq = z16(), gk = z16();
  int l0 = w << 8;
  for (int lc = 0; lc < 16; ++lc) {
    int loff = l0 + (lc << 4) + (hi << 3);
    bf16x8 a0 = cvt8(qa + loff), b0 = cvt8(qc + loff);
    bf16x8 a1 = cvt8(ka + loff), b1 = cvt8(kc + loff);
    gq = __builtin_amdgcn_mfma_f32_32x32x16_bf16(a0, b0, gq, 0, 0, 0);
    gk = __builtin_amdgcn_mfma_f32_32x32x16_bf16(a1, b1, gk, 0, 0, 0);
  }
  // block-reduce the four wave-partial Grams to the full tile, then dot them
  __shared__ float LQ[4][64][16];
  __shared__ float LK[4][64][16];
  #pragma unroll
  for (int r = 0; r < 16; ++r) { LQ[w][lane][r] = gq[r]; LK[w][lane][r] = gk[r]; }
  __syncthreads();
  if (tid < 64) {
    float acc = 0.f;
    #pragma unroll
    for (int r = 0; r < 16; ++r) {
      float a = LQ[0][tid][r] + LQ[1][tid][r] + LQ[2][tid][r] + LQ[3][tid][r];
      float b = LK[0][tid][r] + LK[1][tid][r] + LK[2][tid][r] + LK[3][tid][r];
      acc += a * b;
    }
    #pragma unroll
    for (int off = 32; off > 0; off >>= 1) acc += __shfl_down(acc, off, 64);
    if (tid == 0) partial[blockIdx.x] = acc;
  }
}

// ---------------- K1b: scale2_h = gamma_h * rsqrt(var+eps) * log2(e) ----------
__global__ void k1b_scale(const float* __restrict__ partial,
                          const float* __restrict__ gamma_sim,
                          float* __restrict__ scale2) {
  int t = threadIdx.x;
  if (t < 8) {
    float s = 0.f;
    for (int b = 0; b < 8; ++b) {
      int base = ((b << 3) + t) << 2;          // blocks (b*8+t)*4 .. +3
      s += partial[base] + partial[base+1] + partial[base+2] + partial[base+3];
    }
    float var = s * (1.0f / 8388608.0f);       // / (N*L*M); mean^2 term ~1e-9, dropped
    scale2[t] = gamma_sim[t] * rsqrtf(var + 1e-5f) * 1.44269504089f;
  }
}

// ---------------- K2: flash attention, swapped-QK^T 32x32 MFMA ----------------
// grid 512 = (bh, l-slab of 128); 4 waves x 32 l-columns each.
// S^T = mfma(Kt-frag, Q-frag): lane owns column l -> softmax is lane-local.
// P -> PV B-frags via cvt + __shfl_xor(32) cross-half exchange (robust semantics).
__global__ __launch_bounds__(256) void k2_attn(const float* __restrict__ Q,
                                               const short* __restrict__ Kt,
                                               const float* __restrict__ V,
                                               const float* __restrict__ scale2,
                                               float* __restrict__ rv) {
  __shared__ short ldsK[4096];   // [64 m][64 d] bf16, 16B-chunk XOR swizzle
  __shared__ short ldsV[4096];   // [64 c][64 m] bf16, same swizzle
  int bh = blockIdx.x >> 3;
  int l0 = (blockIdx.x & 7) << 7;
  int tid = threadIdx.x, w = tid >> 6, lane = tid & 63;
  int l31 = lane & 31, hi = lane >> 5;
  int lq = l0 + (w << 5) + l31;                  // this lane's l column
  float sc2 = scale2[bh & 7];
  // Q fragments (B operand), kept in registers for whole block
  const float* qb = Q + ((size_t)bh << 16) + lq;
  bf16x8 qf[4];
  #pragma unroll
  for (int kc = 0; kc < 4; ++kc) {
    bf16x8 f;
    #pragma unroll
    for (int i = 0; i < 8; ++i)
      f[i] = (__bf16)qb[(size_t)((kc << 4) + (hi << 3) + i) << 10];
    qf[kc] = f;
  }
  f32x16 o0 = z16(), o1 = z16();
  float rsum = 0.f;
  const short* ktb = Kt + ((size_t)bh << 16);
  const float* vb  = V  + ((size_t)bh << 16);
  for (int mi = 0; mi < 16; ++mi) {
    int m0 = mi << 6;
    __syncthreads();
    #pragma unroll
    for (int it = 0; it < 2; ++it) {           // stage K tile (bf16 from Kt)
      int idx = tid + (it << 8);
      int m = idx >> 3, ch = idx & 7;
      s16x8 kv = *(const s16x8*)(ktb + ((size_t)(m0 + m) << 6) + (ch << 3));
      *(s16x8*)((char*)ldsK + m*128 + ((ch << 4) ^ ((m & 7) << 4))) = kv;
    }
    #pragma unroll
    for (int it = 0; it < 2; ++it) {           // stage V tile (fp32 -> bf16)
      int idx = tid + (it << 8);
      int c = idx >> 3, ch = idx & 7;
      const float* vp = vb + ((size_t)c << 10) + m0 + (ch << 3);
      f32x4 a = *(const f32x4*)vp;
      f32x4 b = *(const f32x4*)(vp + 4);
      s16x8 pv;
      #pragma unroll
      for (int j = 0; j < 4; ++j) { pv[j] = bf16s(a[j]); pv[4+j] = bf16s(b[j]); }
      *(s16x8*)((char*)ldsV + c*128 + ((ch << 4) ^ ((c & 7) << 4))) = pv;
    }
    __syncthreads();
    #pragma unroll
    for (int mt = 0; mt < 2; ++mt) {
      // S^T tile: D[i=m][j=l]
      f32x16 s = z16();
      int mrow = (mt << 5) + l31;
      #pragma unroll
      for (int kc = 0; kc < 4; ++kc) {
        int chunk = (kc << 1) + hi;
        bf16x8 af = *(bf16x8*)((char*)ldsK + mrow*128 + ((chunk << 4) ^ ((mrow & 7) << 4)));
        s = __builtin_amdgcn_mfma_f32_32x32x16_bf16(af, qf[kc], s, 0, 0, 0);
      }
      // softmax numerators (BN bounds logits -> no max subtraction needed)
      float p[16];
      #pragma unroll
      for (int r = 0; r < 16; ++r) { p[r] = exp2f(s[r] * sc2); rsum += p[r]; }
      // dw[j] holds P at m-rows: hi=0: (2j',2j'+1) of {0-3,8-11,16-19,24-27}; hi=1: +4
      unsigned dw[8];
      #pragma unroll
      for (int j = 0; j < 8; ++j) dw[j] = pkbf(p[2*j], p[2*j+1]);
      unsigned t0 = __shfl_xor(dw[0], 32, 64);
      unsigned t1 = __shfl_xor(dw[1], 32, 64);
      unsigned t2 = __shfl_xor(dw[2], 32, 64);
      unsigned t3 = __shfl_xor(dw[3], 32, 64);
      unsigned t4 = __shfl_xor(dw[4], 32, 64);
      unsigned t5 = __shfl_xor(dw[5], 32, 64);
      unsigned t6 = __shfl_xor(dw[6], 32, 64);
      unsigned t7 = __shfl_xor(dw[7], 32, 64);
      // pb0: m 0..15 of tile; pb1: m 16..31.  B layout: lane-group hi holds k=8hi+j.
      bf16x8 pb0 = hi ? mk8(t2, t3, dw[2], dw[3]) : mk8(dw[0], dw[1], t0, t1);
      bf16x8 pb1 = hi ? mk8(t6, t7, dw[6], dw[7]) : mk8(dw[4], dw[5], t4, t5);
      // PV: O^T[c][l] += V[c][m] * P^T[m][l]
      {
        int crow = l31;
        bf16x8 va0 = *(bf16x8*)((char*)ldsV + crow*128 + ((((mt << 2) + hi) << 4) ^ ((crow & 7) << 4)));
        o0 = __builtin_amdgcn_mfma_f32_32x32x16_bf16(va0, pb0, o0, 0, 0, 0);
        bf16x8 va1 = *(bf16x8*)((char*)ldsV + crow*128 + ((((mt << 2) + 2 + hi) << 4) ^ ((crow & 7) << 4)));
        o0 = __builtin_amdgcn_mfma_f32_32x32x16_bf16(va1, pb1, o0, 0, 0, 0);
      }
      {
        int crow = 32 + l31;
        bf16x8 va0 = *(bf16x8*)((char*)ldsV + crow*128 + ((((mt << 2) + hi) << 4) ^ ((crow & 7) << 4)));
        o1 = __builtin_amdgcn_mfma_f32_32x32x16_bf16(va0, pb0, o1, 0, 0, 0);
        bf16x8 va1 = *(bf16x8*)((char*)ldsV + crow*128 + ((((mt << 2) + 2 + hi) << 4) ^ ((crow & 7) << 4)));
        o1 = __builtin_amdgcn_mfma_f32_32x32x16_bf16(va1, pb1, o1, 0, 0, 0);
      }
    }
  }
  // finalize: row sum = own half + twin half (same column l)
  float tot = rsum + __shfl_xor(rsum, 32, 64);
  float inv = 1.0f / tot;
  #pragma unroll
  for (int r = 0; r < 16; ++r) {
    int cr = (r & 3) + ((r >> 2) << 3) + (hi << 2);
    rv[((size_t)(bh*64 + cr) << 10) + lq] = o0[r] * inv;
  }
  #pragma unroll
  for (int r = 0; r < 16; ++r) {
    int cr = 32 + (r & 3) + ((r >> 2) << 3) + (hi << 2);
    rv[((size_t)(bh*64 + cr) << 10) + lq] = o1[r] * inv;
  }
}

// ---------------- K34: per-channel BatchNorm1d + exact GELU (in-place) --------
__global__ __launch_bounds__(256) void k34_bn_gelu(const float* rv,
                                                   const float* __restrict__ gamma_v,
                                                   const float* __restrict__ beta_v,
                                                   float* out) {
  int ch = blockIdx.x;
  int tid = threadIdx.x, w = tid >> 6, lane = tid & 63;
  float s = 0.f, s2 = 0.f;
  #pragma unroll
  for (int b = 0; b < 8; ++b) {
    f32x4 x = *(const f32x4*)(rv + (((size_t)(b*512 + ch)) << 10) + (tid << 2));
    #pragma unroll
    for (int j = 0; j < 4; ++j) { s += x[j]; s2 += x[j]*x[j]; }
  }
  #pragma unroll
  for (int off = 32; off > 0; off >>= 1) { s += __shfl_down(s, off, 64); s2 += __shfl_down(s2, off, 64); }
  __shared__ float red0[4], red1[4];
  __shared__ float ab[2];
  if (lane == 0) { red0[w] = s; red1[w] = s2; }
  __syncthreads();
  if (tid == 0) {
    float S  = red0[0] + red0[1] + red0[2] + red0[3];
    float S2 = red1[0] + red1[1] + red1[2] + red1[3];
    float mean = S * (1.0f / 8192.0f);
    float var  = S2 * (1.0f / 8192.0f) - mean * mean;
    float a = gamma_v[ch] * rsqrtf(var + 1e-5f);
    ab[0] = a; ab[1] = beta_v[ch] - mean * a;
  }
  __syncthreads();
  float a = ab[0], bb = ab[1];
  #pragma unroll
  for (int b = 0; b < 8; ++b) {
    size_t off = (((size_t)(b*512 + ch)) << 10) + (tid << 2);
    f32x4 x = *(const f32x4*)(rv + off);
    f32x4 y;
    #pragma unroll
    for (int j = 0; j < 4; ++j) {
      float v = a * x[j] + bb;
      y[j] = 0.5f * v * (1.0f + erff(v * 0.70710678118f));
    }
    *(f32x4*)(out + off) = y;
  }
}

extern "C" void kernel_launch(void* const* d_in, const int* in_sizes, int n_in,
                              void* d_out, int out_size, void* d_ws, size_t ws_size,
                              hipStream_t stream) {
  const float* q        = (const float*)d_in[0];
  const float* k        = (const float*)d_in[1];
  const float* v        = (const float*)d_in[2];
  const float* gamma_s  = (const float*)d_in[3];
  // d_in[4] = beta_sim: cancels in softmax, unused
  const float* gamma_v  = (const float*)d_in[5];
  const float* beta_v   = (const float*)d_in[6];
  float* out = (float*)d_out;
  char*  ws  = (char*)d_ws;
  short* kt  = (short*)(ws + KT_OFF);
  float* ss  = (float*)(ws + SS_OFF);
  float* sc  = (float*)(ws + SC_OFF);

  k0_transpose<<<1024, 256, 0, stream>>>(k, kt);
  k1_gram     <<<256, 256, 0, stream>>>(q, k, ss);
  k1b_scale   <<<1, 64, 0, stream>>>(ss, gamma_s, sc);
  k2_attn     <<<512, 256, 0, stream>>>(q, kt, v, sc, out);   // rv staged in d_out
  k34_bn_gelu <<<512, 256, 0, stream>>>(out, gamma_v, beta_v, out);  // in-place
}

// Round 3
// 90.962 us; speedup vs baseline: 1.1282x; 1.1282x over previous
//
#include <hip/hip_runtime.h>
#include <hip/hip_bf16.h>
#include <math.h>

// dims fixed by setup_inputs: N=8, H=8, D=64, L=M=1024, C=64

typedef __attribute__((ext_vector_type(4)))  float    f32x4;
typedef __attribute__((ext_vector_type(16))) float    f32x16;
typedef __attribute__((ext_vector_type(8)))  __bf16   bf16x8;
typedef __attribute__((ext_vector_type(8)))  short    s16x8;
typedef __attribute__((ext_vector_type(4)))  unsigned u32x4;

// ws layout (proven footprint: 8 MiB + ~1 KiB)
#define KT_OFF 0u
#define SS_OFF (8u*1024u*1024u)            // fp32 partial[256]
#define SC_OFF (SS_OFF + 1024u)            // fp32 scale2[8]

static __device__ __forceinline__ short bf16s(float f) {
  return __builtin_bit_cast(short, (__bf16)f);
}
static __device__ __forceinline__ unsigned pkbf(float lo, float hi) {
  unsigned l = (unsigned)__builtin_bit_cast(unsigned short, (__bf16)lo);
  unsigned h = (unsigned)__builtin_bit_cast(unsigned short, (__bf16)hi);
  return l | (h << 16);
}
static __device__ __forceinline__ bf16x8 cvt8(const float* p) {
  f32x4 a = *(const f32x4*)p;
  f32x4 b = *(const f32x4*)(p + 4);
  bf16x8 r;
  r[0]=(__bf16)a[0]; r[1]=(__bf16)a[1]; r[2]=(__bf16)a[2]; r[3]=(__bf16)a[3];
  r[4]=(__bf16)b[0]; r[5]=(__bf16)b[1]; r[6]=(__bf16)b[2]; r[7]=(__bf16)b[3];
  return r;
}
static __device__ __forceinline__ f32x16 z16() {
  f32x16 z;
  #pragma unroll
  for (int i = 0; i < 16; ++i) z[i] = 0.f;
  return z;
}
static __device__ __forceinline__ bf16x8 mk8(unsigned a, unsigned b, unsigned c, unsigned d) {
  u32x4 u; u[0]=a; u[1]=b; u[2]=c; u[3]=d;
  return __builtin_bit_cast(bf16x8, u);
}
static __device__ __forceinline__ void gll16(const void* g, void* l) {
  __builtin_amdgcn_global_load_lds(
      (const __attribute__((address_space(1))) void*)g,
      (__attribute__((address_space(3))) void*)l, 16, 0, 0);
}

// ---------------- K0: K [bh][d][m] fp32 -> Kt [bh][m][d] bf16 ----------------
__global__ __launch_bounds__(256) void k0_transpose(const float* __restrict__ K,
                                                    short* __restrict__ Kt) {
  int bh = blockIdx.x >> 4;
  int m0 = (blockIdx.x & 15) << 6;
  __shared__ short tile[64][72];          // [m][d], +8 pad
  int tid = threadIdx.x;
  int d = tid >> 2;
  #pragma unroll
  for (int it = 0; it < 4; ++it) {
    int mc4 = (tid & 3) + (it << 2);      // 16 chunks of 4 m
    const f32x4 v = *(const f32x4*)(K + (((size_t)(bh*64 + d)) << 10) + m0 + (mc4 << 2));
    #pragma unroll
    for (int j = 0; j < 4; ++j) tile[mc4*4 + j][d] = bf16s(v[j]);
  }
  __syncthreads();
  int m = tid >> 2, q = tid & 3;
  s16x8 o0, o1;
  #pragma unroll
  for (int j = 0; j < 8; ++j) { o0[j] = tile[m][q*16 + j]; o1[j] = tile[m][q*16 + 8 + j]; }
  short* dst = Kt + ((size_t)bh << 16) + ((size_t)(m0 + m) << 6) + (q << 4);
  *(s16x8*)dst = o0;
  *(s16x8*)(dst + 8) = o1;
}

// ---------------- K1: partial[blk] = <GQ_tile, GK_tile> (deterministic) ------
__global__ __launch_bounds__(256) void k1_gram(const float* __restrict__ Q,
                                               const float* __restrict__ K,
                                               float* __restrict__ partial) {
  int bh = blockIdx.x >> 2;
  int t  = blockIdx.x & 3;
  int tr = (t >> 1) << 5, tc = (t & 1) << 5;
  int tid = threadIdx.x, w = tid >> 6, lane = tid & 63;
  int l31 = lane & 31, hi = lane >> 5;
  const float* qb = Q + ((size_t)bh << 16);
  const float* kb = K + ((size_t)bh << 16);
  const float* qa = qb + ((size_t)(tr + l31) << 10);
  const float* qc = qb + ((size_t)(tc + l31) << 10);
  const float* ka = kb + ((size_t)(tr + l31) << 10);
  const float* kc = kb + ((size_t)(tc + l31) << 10);
  f32x16 gq = z16(), gk = z16();
  int l0 = w << 8;
  for (int lc = 0; lc < 16; ++lc) {
    int loff = l0 + (lc << 4) + (hi << 3);
    bf16x8 a0 = cvt8(qa + loff), b0 = cvt8(qc + loff);
    bf16x8 a1 = cvt8(ka + loff), b1 = cvt8(kc + loff);
    gq = __builtin_amdgcn_mfma_f32_32x32x16_bf16(a0, b0, gq, 0, 0, 0);
    gk = __builtin_amdgcn_mfma_f32_32x32x16_bf16(a1, b1, gk, 0, 0, 0);
  }
  __shared__ float LQ[4][64][16];
  __shared__ float LK[4][64][16];
  #pragma unroll
  for (int r = 0; r < 16; ++r) { LQ[w][lane][r] = gq[r]; LK[w][lane][r] = gk[r]; }
  __syncthreads();
  if (tid < 64) {
    float acc = 0.f;
    #pragma unroll
    for (int r = 0; r < 16; ++r) {
      float a = LQ[0][tid][r] + LQ[1][tid][r] + LQ[2][tid][r] + LQ[3][tid][r];
      float b = LK[0][tid][r] + LK[1][tid][r] + LK[2][tid][r] + LK[3][tid][r];
      acc += a * b;
    }
    #pragma unroll
    for (int off = 32; off > 0; off >>= 1) acc += __shfl_down(acc, off, 64);
    if (tid == 0) partial[blockIdx.x] = acc;
  }
}

// ---------------- K1b: scale2_h = gamma_h * rsqrt(var+eps) * log2(e) ----------
__global__ void k1b_scale(const float* __restrict__ partial,
                          const float* __restrict__ gamma_sim,
                          float* __restrict__ scale2) {
  int t = threadIdx.x;
  if (t < 8) {
    float s = 0.f;
    for (int b = 0; b < 8; ++b) {
      int base = ((b << 3) + t) << 2;
      s += partial[base] + partial[base+1] + partial[base+2] + partial[base+3];
    }
    float var = s * (1.0f / 8388608.0f);       // / (N*L*M); mean^2 term ~1e-9, dropped
    scale2[t] = gamma_sim[t] * rsqrtf(var + 1e-5f) * 1.44269504089f;
  }
}

// ---------------- K2: flash attention, dbuf pipeline, swapped-QK^T 32x32 ------
// grid 512; XCD-swizzled so the 8 l-slabs of one bh share an XCD's L2.
// Per iter t: [ds_write V(t+1) | gll K(t+1) | vload V(t+2)] overlap compute(t).
__global__ __launch_bounds__(256) void k2_attn(const float* __restrict__ Q,
                                               const short* __restrict__ Kt,
                                               const float* __restrict__ V,
                                               const float* __restrict__ scale2,
                                               float* __restrict__ rv) {
  __shared__ short ldsK[2][4096];   // [64 m][8 chunks of 8 d] bf16, XOR-swizzled chunks
  __shared__ short ldsV[2][4096];   // [64 c][8 chunks of 8 m] bf16, same swizzle
  int b = blockIdx.x;
  int bh   = (b & 7) + (((b >> 3) & 7) << 3);   // same bh -> same XCD (round-robin %8)
  int slab = b >> 6;
  int l0 = slab << 7;
  int tid = threadIdx.x, w = tid >> 6, lane = tid & 63;
  int l31 = lane & 31, hi = lane >> 5;
  int lq = l0 + (w << 5) + l31;
  float sc2 = scale2[bh & 7];
  const short* ktb = Kt + ((size_t)bh << 16);
  const float* vb  = V  + ((size_t)bh << 16);
  const float* qb  = Q  + ((size_t)bh << 16) + lq;

  // Q fragments (B operand), registers for whole block
  bf16x8 qf[4];
  #pragma unroll
  for (int kc = 0; kc < 4; ++kc) {
    bf16x8 f;
    #pragma unroll
    for (int i = 0; i < 8; ++i)
      f[i] = (__bf16)qb[(size_t)((kc << 4) + (hi << 3) + i) << 10];
    qf[kc] = f;
  }

  // per-thread staging coords
  f32x4 va[4];                       // V prefetch regs (16 floats, tile t+2)
  // prologue: K(0) via gll, V(0) direct, V(1) -> regs
  #pragma unroll
  for (int p = 0; p < 2; ++p) {
    int idx = (p << 8) + tid, row = idx >> 3, ch = idx & 7;
    gll16(ktb + ((size_t)row << 6) + ((ch ^ (row & 7)) << 3), &ldsK[0][idx << 3]);
  }
  #pragma unroll
  for (int p = 0; p < 2; ++p) {
    int idx = (p << 8) + tid, row = idx >> 3, ch = idx & 7;
    const float* vp = vb + ((size_t)row << 10) + (ch << 3);
    f32x4 a = *(const f32x4*)vp, c = *(const f32x4*)(vp + 4);
    s16x8 pv;
    #pragma unroll
    for (int j = 0; j < 4; ++j) { pv[j] = bf16s(a[j]); pv[4+j] = bf16s(c[j]); }
    *(s16x8*)&ldsV[0][(row << 6) + ((ch ^ (row & 7)) << 3)] = pv;
  }
  #pragma unroll
  for (int p = 0; p < 2; ++p) {
    int idx = (p << 8) + tid, row = idx >> 3, ch = idx & 7;
    const float* vp = vb + ((size_t)row << 10) + 64 + (ch << 3);
    va[2*p] = *(const f32x4*)vp; va[2*p+1] = *(const f32x4*)(vp + 4);
  }
  __syncthreads();

  f32x16 o0 = z16(), o1 = z16();
  float rsum = 0.f;

  for (int t = 0; t < 16; ++t) {
    int cur = t & 1, nxt = cur ^ 1;
    if (t < 15) {
      // ds_write V(t+1) from regs (buffer nxt was sync-protected last iter)
      #pragma unroll
      for (int p = 0; p < 2; ++p) {
        int idx = (p << 8) + tid, row = idx >> 3, ch = idx & 7;
        s16x8 pv;
        #pragma unroll
        for (int j = 0; j < 4; ++j) { pv[j] = bf16s(va[2*p][j]); pv[4+j] = bf16s(va[2*p+1][j]); }
        *(s16x8*)&ldsV[nxt][(row << 6) + ((ch ^ (row & 7)) << 3)] = pv;
      }
      // async K(t+1) -> LDS (drains at end-of-iter syncthreads, hidden by compute)
      int m1 = (t + 1) << 6;
      #pragma unroll
      for (int p = 0; p < 2; ++p) {
        int idx = (p << 8) + tid, row = idx >> 3, ch = idx & 7;
        gll16(ktb + ((size_t)(m1 + row) << 6) + ((ch ^ (row & 7)) << 3), &ldsK[nxt][idx << 3]);
      }
      if (t < 14) {
        int m2 = (t + 2) << 6;
        #pragma unroll
        for (int p = 0; p < 2; ++p) {
          int idx = (p << 8) + tid, row = idx >> 3, ch = idx & 7;
          const float* vp = vb + ((size_t)row << 10) + m2 + (ch << 3);
          va[2*p] = *(const f32x4*)vp; va[2*p+1] = *(const f32x4*)(vp + 4);
        }
      }
    }
    // ---- compute tile t from buffers [cur] ----
    #pragma unroll
    for (int mt = 0; mt < 2; ++mt) {
      f32x16 s = z16();
      int mrow = (mt << 5) + l31;
      __builtin_amdgcn_s_setprio(1);
      #pragma unroll
      for (int kc = 0; kc < 4; ++kc) {
        int chunk = (kc << 1) + hi;
        bf16x8 af = *(bf16x8*)((char*)&ldsK[cur][0] + mrow*128 + ((chunk << 4) ^ ((mrow & 7) << 4)));
        s = __builtin_amdgcn_mfma_f32_32x32x16_bf16(af, qf[kc], s, 0, 0, 0);
      }
      __builtin_amdgcn_s_setprio(0);
      float p[16];
      #pragma unroll
      for (int r = 0; r < 16; ++r) { p[r] = exp2f(s[r] * sc2); rsum += p[r]; }
      unsigned dw[8];
      #pragma unroll
      for (int j = 0; j < 8; ++j) dw[j] = pkbf(p[2*j], p[2*j+1]);
      unsigned t0 = __shfl_xor(dw[0], 32, 64);
      unsigned t1 = __shfl_xor(dw[1], 32, 64);
      unsigned t2 = __shfl_xor(dw[2], 32, 64);
      unsigned t3 = __shfl_xor(dw[3], 32, 64);
      unsigned t4 = __shfl_xor(dw[4], 32, 64);
      unsigned t5 = __shfl_xor(dw[5], 32, 64);
      unsigned t6 = __shfl_xor(dw[6], 32, 64);
      unsigned t7 = __shfl_xor(dw[7], 32, 64);
      bf16x8 pb0 = hi ? mk8(t2, t3, dw[2], dw[3]) : mk8(dw[0], dw[1], t0, t1);
      bf16x8 pb1 = hi ? mk8(t6, t7, dw[6], dw[7]) : mk8(dw[4], dw[5], t4, t5);
      __builtin_amdgcn_s_setprio(1);
      {
        int crow = l31;
        bf16x8 va0 = *(bf16x8*)((char*)&ldsV[cur][0] + crow*128 + ((((mt << 2) + hi) << 4) ^ ((crow & 7) << 4)));
        o0 = __builtin_amdgcn_mfma_f32_32x32x16_bf16(va0, pb0, o0, 0, 0, 0);
        bf16x8 va1 = *(bf16x8*)((char*)&ldsV[cur][0] + crow*128 + ((((mt << 2) + 2 + hi) << 4) ^ ((crow & 7) << 4)));
        o0 = __builtin_amdgcn_mfma_f32_32x32x16_bf16(va1, pb1, o0, 0, 0, 0);
      }
      {
        int crow = 32 + l31;
        bf16x8 va0 = *(bf16x8*)((char*)&ldsV[cur][0] + crow*128 + ((((mt << 2) + hi) << 4) ^ ((crow & 7) << 4)));
        o1 = __builtin_amdgcn_mfma_f32_32x32x16_bf16(va0, pb0, o1, 0, 0, 0);
        bf16x8 va1 = *(bf16x8*)((char*)&ldsV[cur][0] + crow*128 + ((((mt << 2) + 2 + hi) << 4) ^ ((crow & 7) << 4)));
        o1 = __builtin_amdgcn_mfma_f32_32x32x16_bf16(va1, pb1, o1, 0, 0, 0);
      }
      __builtin_amdgcn_s_setprio(0);
    }
    __syncthreads();
  }
  // finalize: softmax denominator = own half + twin half (same column l)
  float tot = rsum + __shfl_xor(rsum, 32, 64);
  float inv = 1.0f / tot;
  #pragma unroll
  for (int r = 0; r < 16; ++r) {
    int cr = (r & 3) + ((r >> 2) << 3) + (hi << 2);
    rv[((size_t)(bh*64 + cr) << 10) + lq] = o0[r] * inv;
  }
  #pragma unroll
  for (int r = 0; r < 16; ++r) {
    int cr = 32 + (r & 3) + ((r >> 2) << 3) + (hi << 2);
    rv[((size_t)(bh*64 + cr) << 10) + lq] = o1[r] * inv;
  }
}

// ---------------- K34: per-channel BatchNorm1d + exact GELU (in-place) --------
__global__ __launch_bounds__(256) void k34_bn_gelu(const float* rv,
                                                   const float* __restrict__ gamma_v,
                                                   const float* __restrict__ beta_v,
                                                   float* out) {
  int ch = blockIdx.x;
  int tid = threadIdx.x, w = tid >> 6, lane = tid & 63;
  float s = 0.f, s2 = 0.f;
  #pragma unroll
  for (int b = 0; b < 8; ++b) {
    f32x4 x = *(const f32x4*)(rv + (((size_t)(b*512 + ch)) << 10) + (tid << 2));
    #pragma unroll
    for (int j = 0; j < 4; ++j) { s += x[j]; s2 += x[j]*x[j]; }
  }
  #pragma unroll
  for (int off = 32; off > 0; off >>= 1) { s += __shfl_down(s, off, 64); s2 += __shfl_down(s2, off, 64); }
  __shared__ float red0[4], red1[4];
  __shared__ float ab[2];
  if (lane == 0) { red0[w] = s; red1[w] = s2; }
  __syncthreads();
  if (tid == 0) {
    float S  = red0[0] + red0[1] + red0[2] + red0[3];
    float S2 = red1[0] + red1[1] + red1[2] + red1[3];
    float mean = S * (1.0f / 8192.0f);
    float var  = S2 * (1.0f / 8192.0f) - mean * mean;
    float a = gamma_v[ch] * rsqrtf(var + 1e-5f);
    ab[0] = a; ab[1] = beta_v[ch] - mean * a;
  }
  __syncthreads();
  float a = ab[0], bb = ab[1];
  #pragma unroll
  for (int b = 0; b < 8; ++b) {
    size_t off = (((size_t)(b*512 + ch)) << 10) + (tid << 2);
    f32x4 x = *(const f32x4*)(rv + off);
    f32x4 y;
    #pragma unroll
    for (int j = 0; j < 4; ++j) {
      float v = a * x[j] + bb;
      y[j] = 0.5f * v * (1.0f + erff(v * 0.70710678118f));
    }
    *(f32x4*)(out + off) = y;
  }
}

extern "C" void kernel_launch(void* const* d_in, const int* in_sizes, int n_in,
                              void* d_out, int out_size, void* d_ws, size_t ws_size,
                              hipStream_t stream) {
  const float* q        = (const float*)d_in[0];
  const float* k        = (const float*)d_in[1];
  const float* v        = (const float*)d_in[2];
  const float* gamma_s  = (const float*)d_in[3];
  // d_in[4] = beta_sim: cancels in softmax, unused
  const float* gamma_v  = (const float*)d_in[5];
  const float* beta_v   = (const float*)d_in[6];
  float* out = (float*)d_out;
  char*  ws  = (char*)d_ws;
  short* kt  = (short*)(ws + KT_OFF);
  float* ss  = (float*)(ws + SS_OFF);
  float* sc  = (float*)(ws + SC_OFF);

  k0_transpose<<<1024, 256, 0, stream>>>(k, kt);
  k1_gram     <<<256, 256, 0, stream>>>(q, k, ss);
  k1b_scale   <<<1, 64, 0, stream>>>(ss, gamma_s, sc);
  k2_attn     <<<512, 256, 0, stream>>>(q, kt, v, sc, out);   // rv staged in d_out
  k34_bn_gelu <<<512, 256, 0, stream>>>(out, gamma_v, beta_v, out);  // in-place
}